// Round 8
// baseline (390.552 us; speedup 1.0000x reference)
//
#include <hip/hip_runtime.h>
#include <hip/hip_runtime_api.h>

#define NNODES 50000
#define NEDGES 800000
#define GG 32
#define KCUR 16
#define FIN 128
#define HIDN 64
#define NHEADS 4
#define F1 256          // NHEADS*HIDN
#define NCHUNK 196      // ceil(NNODES/256)
#define HBLK 3125       // NEDGES/256 hist/scatter blocks
#define GBLK 782        // ceil(NNODES/64) gemm1 blocks

typedef unsigned short u16;
typedef unsigned char u8;
typedef short bf8 __attribute__((ext_vector_type(8)));    // 8 bf16 in 4 VGPRs
typedef float f32x4 __attribute__((ext_vector_type(4)));

// ---- bf16 helpers ----
__device__ __forceinline__ u16 f2bf(float f) {
    unsigned u = __float_as_uint(f);
    return (u16)((u + 0x7fffu + ((u >> 16) & 1u)) >> 16);   // RNE
}
__device__ __forceinline__ float lrelu(float x) { return x > 0.f ? x : 0.2f * x; }
// fp8 e4m3 HW converts
__device__ __forceinline__ unsigned pk4fp8(float a, float b, float c, float d) {
    unsigned u = __builtin_amdgcn_cvt_pk_fp8_f32(a, b, 0u, false);
    u = __builtin_amdgcn_cvt_pk_fp8_f32(c, d, u, true);
    return u;
}
template<int SEL>
__device__ __forceinline__ float fp8f(unsigned v) {
    return __builtin_amdgcn_cvt_f32_fp8(v, SEL);   // SEL must be compile-time const
}

// ---------------- fused: edge histogram + weight pack ----------------
// blocks [0,HBLK): histogram of dst. blocks [HBLK, HBLK+192): pack W1/W2 fp32->
// bf16 MFMA fragment order: Wp[((t*S+s)*64+l)*8+j] = W[s*32+(l>>4)*8+j][t*16+(l&15)]
__global__ __launch_bounds__(256)
void hist_pack_k(const int* __restrict__ dst, int* __restrict__ deg,
                 const float* __restrict__ W1, const float* __restrict__ W2,
                 u16* __restrict__ W1p, u16* __restrict__ W2p)
{
    if (blockIdx.x < HBLK) {
        int e = blockIdx.x * 256 + threadIdx.x;
        if (e < NEDGES) atomicAdd(&deg[dst[e]], 1);
        return;
    }
    int idx = (blockIdx.x - HBLK) * 256 + threadIdx.x;
    const float* src; u16* dstp; int S, N, li;
    if (idx < 32768) { src = W1; dstp = W1p; S = FIN / 32; N = F1; li = idx; }
    else if (idx < 49152) { src = W2; dstp = W2p; S = F1 / 32; N = HIDN; li = idx - 32768; }
    else return;
    int j = li & 7, l = (li >> 3) & 63, rest = li >> 9;
    int s = rest % S, t = rest / S;
    int k = s * 32 + (l >> 4) * 8 + j;
    int n = t * 16 + (l & 15);
    dstp[li] = f2bf(src[(size_t)k * N + n]);
}

// ---------------- expand: rowptr/cursor; block offset self-computed ----------
__global__ __launch_bounds__(256)
void expand_k(const int* __restrict__ deg, int* __restrict__ rowptr,
              int* __restrict__ cursor)
{
    __shared__ int ws[4], ws2[4];
    __shared__ int boffs;
    int tid = threadIdx.x, lane = tid & 63, wid = tid >> 6;
    // sum of deg[0 .. bx*256) — redundant per-block compute beats a launch
    int v0 = 0;
    for (int b = 0; b < (int)blockIdx.x; b++) v0 += deg[b * 256 + tid];
#pragma unroll
    for (int o = 32; o; o >>= 1) v0 += __shfl_down(v0, o);
    if (lane == 0) ws[wid] = v0;
    __syncthreads();
    if (tid == 0) boffs = ws[0] + ws[1] + ws[2] + ws[3];
    __syncthreads();
    int i = blockIdx.x * 256 + tid;
    int v = (i < NNODES) ? deg[i] : 0;
    int x = v;
#pragma unroll
    for (int o = 1; o < 64; o <<= 1) {
        int y = __shfl_up(x, o);
        if (lane >= o) x += y;
    }
    if (lane == 63) ws2[wid] = x;
    __syncthreads();
    int off = boffs;
    for (int w = 0; w < wid; w++) off += ws2[w];
    int excl = off + x - v;
    if (i < NNODES) { rowptr[i] = excl; cursor[i] = excl; }
    if (i == 0) rowptr[NNODES] = NEDGES;
}

// ---------------- fused: CSR scatter + GEMM1 (x@W1 -> fp8 h1, att dots) -------
__global__ __launch_bounds__(256)
void scat_gemm1_k(const int* __restrict__ src, const int* __restrict__ dst,
                  int* __restrict__ cursor, int* __restrict__ csr,
                  const float* __restrict__ X, const u16* __restrict__ Bp,
                  const float* __restrict__ att_s, const float* __restrict__ att_d,
                  u8* __restrict__ h1f8, float* __restrict__ as1, float* __restrict__ ad1)
{
    if (blockIdx.x < HBLK) {
        int e = blockIdx.x * 256 + threadIdx.x;
        if (e < NEDGES) {
            int d = dst[e];
            int pos = atomicAdd(&cursor[d], 1);
            csr[pos] = src[e];
        }
        return;
    }
    // ---- gemm1: swapped-operand MFMA, D = Wp·Xp so lane holds 4 consecutive
    // output channels of one node -> one u32 fp8 store. head = wave id.
    const int S = FIN / 32;  // 4
    int lane = threadIdx.x & 63, w = threadIdx.x >> 6;
    int m0 = (blockIdx.x - HBLK) * 64;
    int row_in = lane & 15, kq = lane >> 4;
    f32x4 acc[4][4];
#pragma unroll
    for (int r = 0; r < 4; r++)
#pragma unroll
        for (int tt = 0; tt < 4; tt++) acc[r][tt] = (f32x4){0.f, 0.f, 0.f, 0.f};
    int R = (NNODES - m0) >> 4; if (R > 4) R = 4;

    for (int s = 0; s < S; s++) {
        bf8 bfrag[4];
#pragma unroll
        for (int tt = 0; tt < 4; tt++) {
            int t = w * 4 + tt;
            bfrag[tt] = *(const bf8*)(Bp + (((size_t)t * S + s) * 64 + lane) * 8);
        }
        int kb = s * 32 + kq * 8;
        bf8 af[4];
#pragma unroll
        for (int r = 0; r < 4; r++)
            if (r < R) {
                const float* xp = X + (size_t)(m0 + r * 16 + row_in) * FIN + kb;
                float4 x0 = *(const float4*)xp;
                float4 x1 = *(const float4*)(xp + 4);
                bf8 a;
                a[0] = (short)f2bf(x0.x); a[1] = (short)f2bf(x0.y);
                a[2] = (short)f2bf(x0.z); a[3] = (short)f2bf(x0.w);
                a[4] = (short)f2bf(x1.x); a[5] = (short)f2bf(x1.y);
                a[6] = (short)f2bf(x1.z); a[7] = (short)f2bf(x1.w);
                af[r] = a;
            }
#pragma unroll
        for (int r = 0; r < 4; r++)
            if (r < R)
#pragma unroll
                for (int tt = 0; tt < 4; tt++)
                    acc[r][tt] = __builtin_amdgcn_mfma_f32_16x16x32_bf16(bfrag[tt], af[r], acc[r][tt], 0, 0, 0);
    }
    float attS[16], attD[16];
#pragma unroll
    for (int tt = 0; tt < 4; tt++)
#pragma unroll
        for (int v = 0; v < 4; v++) {
            attS[tt * 4 + v] = att_s[w * 64 + tt * 16 + kq * 4 + v];
            attD[tt * 4 + v] = att_d[w * 64 + tt * 16 + kq * 4 + v];
        }
#pragma unroll
    for (int r = 0; r < 4; r++) {
        if (r >= R) break;
        int node = m0 + r * 16 + row_in;
        float pa = 0.f, pd = 0.f;
#pragma unroll
        for (int tt = 0; tt < 4; tt++) {
            unsigned u = pk4fp8(acc[r][tt][0], acc[r][tt][1], acc[r][tt][2], acc[r][tt][3]);
            *(unsigned*)(h1f8 + (size_t)node * F1 + (w * 4 + tt) * 16 + kq * 4) = u;
#pragma unroll
            for (int v = 0; v < 4; v++) {
                pa = fmaf(acc[r][tt][v], attS[tt * 4 + v], pa);
                pd = fmaf(acc[r][tt][v], attD[tt * 4 + v], pd);
            }
        }
        pa += __shfl_xor(pa, 16); pa += __shfl_xor(pa, 32);
        pd += __shfl_xor(pd, 16); pd += __shfl_xor(pd, 32);
        if (kq == 0) { as1[node * 4 + w] = pa; ad1[node * 4 + w] = pd; }
    }
}

// ---------------- fused gagg1 + GEMM2: aggregate 16 dst into LDS, then MFMA ----
// Phase A: each wave aggregates 4 dst sequentially (half-wave edge pairing,
// fp8 gathers), writes relu'd bf16 rows to LDS (row pad +8 -> 2-way bank = free).
// Phase B: 16x16x32 MFMA vs W2p (wave w = cols w*16..+15), fp8 h2 store +
// fused layer-2 att dots. h1r never touches global memory.
__global__ __launch_bounds__(256)
void gagg1_k(const int* __restrict__ rowptr, const int* __restrict__ csr,
             const float* __restrict__ as1, const float* __restrict__ ad1,
             const u8* __restrict__ h1f8, const float* __restrict__ b1,
             const u16* __restrict__ W2p,
             const float* __restrict__ att_s, const float* __restrict__ att_d,
             u8* __restrict__ h2f8, float* __restrict__ as2, float* __restrict__ ad2)
{
    __shared__ u16 h1s[16][264];
    __shared__ float asl[4][16], adl[4][16];
    int wid = threadIdx.x >> 6, lane = threadIdx.x & 63;
    int m0 = blockIdx.x * 16;                    // NNODES = 3125*16 exactly
    int half = lane >> 5, l31 = lane & 31;
    int h = l31 >> 3, c0 = l31 << 3;

    // ---- Phase A: aggregation ----
#pragma unroll 1
    for (int i = 0; i < 4; i++) {
        int lr = wid * 4 + i;
        int d = m0 + lr;
        int beg = rowptr[d];
        int tot = rowptr[d + 1] - beg + 1;       // + self loop
        float adh = ad1[d * 4 + h];
        float den = 0.f;
        float acc[8];
#pragma unroll
        for (int j = 0; j < 8; j++) acc[j] = 0.f;
        for (int p = half; p < tot; p += 2) {
            int s = (p == 0) ? d : csr[beg + p - 1];
            float ex = __expf(lrelu(as1[s * 4 + h] + adh));
            den += ex;
            uint2 hv = *(const uint2*)(h1f8 + (size_t)s * F1 + c0);
            acc[0] = fmaf(ex, fp8f<0>(hv.x), acc[0]);
            acc[1] = fmaf(ex, fp8f<1>(hv.x), acc[1]);
            acc[2] = fmaf(ex, fp8f<2>(hv.x), acc[2]);
            acc[3] = fmaf(ex, fp8f<3>(hv.x), acc[3]);
            acc[4] = fmaf(ex, fp8f<0>(hv.y), acc[4]);
            acc[5] = fmaf(ex, fp8f<1>(hv.y), acc[5]);
            acc[6] = fmaf(ex, fp8f<2>(hv.y), acc[6]);
            acc[7] = fmaf(ex, fp8f<3>(hv.y), acc[7]);
        }
        den += __shfl_xor(den, 32);
#pragma unroll
        for (int j = 0; j < 8; j++) acc[j] += __shfl_xor(acc[j], 32);
        if (lane < 32) {
            float rden = 1.f / den;
            float4 blo = *(const float4*)(b1 + c0);
            float4 bhi = *(const float4*)(b1 + c0 + 4);
            float bb[8] = {blo.x, blo.y, blo.z, blo.w, bhi.x, bhi.y, bhi.z, bhi.w};
            bf8 o;
#pragma unroll
            for (int j = 0; j < 8; j++)
                o[j] = (short)f2bf(fmaxf(fmaf(acc[j], rden, bb[j]), 0.f));
            *(bf8*)&h1s[lr][c0] = o;
        }
    }
    __syncthreads();

    // ---- Phase B: MFMA h2 = h1s @ W2 (swapped operands) ----
    const int S = F1 / 32;   // 8
    int row_in = lane & 15, kq = lane >> 4;
    f32x4 acc2 = (f32x4){0.f, 0.f, 0.f, 0.f};
#pragma unroll
    for (int s = 0; s < S; s++) {
        bf8 bfrag = *(const bf8*)(W2p + (((size_t)wid * S + s) * 64 + lane) * 8);
        bf8 af = *(const bf8*)&h1s[row_in][s * 32 + kq * 8];
        acc2 = __builtin_amdgcn_mfma_f32_16x16x32_bf16(bfrag, af, acc2, 0, 0, 0);
    }
    int node = m0 + row_in;
    unsigned u = pk4fp8(acc2[0], acc2[1], acc2[2], acc2[3]);
    *(unsigned*)(h2f8 + (size_t)node * HIDN + wid * 16 + kq * 4) = u;
    float pa = 0.f, pd = 0.f;
#pragma unroll
    for (int v = 0; v < 4; v++) {
        pa = fmaf(acc2[v], att_s[wid * 16 + kq * 4 + v], pa);
        pd = fmaf(acc2[v], att_d[wid * 16 + kq * 4 + v], pd);
    }
    pa += __shfl_xor(pa, 16); pa += __shfl_xor(pa, 32);
    pd += __shfl_xor(pd, 16); pd += __shfl_xor(pd, 32);
    if (kq == 0) { asl[wid][row_in] = pa; adl[wid][row_in] = pd; }
    __syncthreads();
    int tid = threadIdx.x;
    if (tid < 16) {
        as2[m0 + tid] = asl[0][tid] + asl[1][tid] + asl[2][tid] + asl[3][tid];
        ad2[m0 + tid] = adl[0][tid] + adl[1][tid] + adl[2][tid] + adl[3][tid];
    }
}

// ---------------- layer-2 gather aggregation (fp8) + fused node score ---------
__global__ __launch_bounds__(256)
void gagg2(const int* __restrict__ rowptr, const int* __restrict__ csr,
           const float* __restrict__ as2, const float* __restrict__ ad2,
           const u8* __restrict__ h2f8, const float* __restrict__ b2,
           const float* __restrict__ aw, const float* __restrict__ ab,
           float* __restrict__ outp, float* __restrict__ scores)
{
    int wid = threadIdx.x >> 6, lane = threadIdx.x & 63;
    int d = blockIdx.x * 4 + wid;
    if (d >= NNODES) return;
    int beg = rowptr[d];
    int tot = rowptr[d + 1] - beg + 1;
    int q = lane >> 4;
    int c0 = (lane & 15) << 2;
    float ads = ad2[d];
    float den = 0.f;
    float a0 = 0.f, a1 = 0.f, a2 = 0.f, a3 = 0.f;

    for (int p = q; p < tot; p += 4) {
        int s = (p == 0) ? d : csr[beg + p - 1];
        float ex = __expf(lrelu(as2[s] + ads));
        den += ex;
        unsigned hv = *(const unsigned*)(h2f8 + (size_t)s * HIDN + c0);
        a0 = fmaf(ex, fp8f<0>(hv), a0);
        a1 = fmaf(ex, fp8f<1>(hv), a1);
        a2 = fmaf(ex, fp8f<2>(hv), a2);
        a3 = fmaf(ex, fp8f<3>(hv), a3);
    }
    den += __shfl_xor(den, 16);  a0 += __shfl_xor(a0, 16);
    a1 += __shfl_xor(a1, 16);    a2 += __shfl_xor(a2, 16);
    a3 += __shfl_xor(a3, 16);
    den += __shfl_xor(den, 32);  a0 += __shfl_xor(a0, 32);
    a1 += __shfl_xor(a1, 32);    a2 += __shfl_xor(a2, 32);
    a3 += __shfl_xor(a3, 32);

    float rden = 1.f / den;
    float4 bb = *(const float4*)(b2 + c0);
    float o0 = fmaf(a0, rden, bb.x);
    float o1 = fmaf(a1, rden, bb.y);
    float o2 = fmaf(a2, rden, bb.z);
    float o3 = fmaf(a3, rden, bb.w);
    if (lane < 16) {
        float4 o = make_float4(o0, o1, o2, o3);
        *(float4*)(outp + (size_t)d * HIDN + c0) = o;
    }
    float p_ = o0 * aw[c0] + o1 * aw[c0 + 1] + o2 * aw[c0 + 2] + o3 * aw[c0 + 3];
    p_ += __shfl_xor(p_, 1); p_ += __shfl_xor(p_, 2);
    p_ += __shfl_xor(p_, 4); p_ += __shfl_xor(p_, 8);
    if (lane == 0) scores[d] = tanhf(p_ + ab[0]);
}

// ---------------- masked online-softmax partials + last-block combine ---------
__global__ __launch_bounds__(256)
void partials_k(const float* __restrict__ scores, const int* __restrict__ masks,
                const float* __restrict__ hf, const int* __restrict__ cur_nodes,
                const int* __restrict__ cur_counts, const float* __restrict__ sw,
                const float* __restrict__ sb,
                float* __restrict__ pmax, float* __restrict__ psum,
                int* __restrict__ pcnt,
                float* __restrict__ gmax, float* __restrict__ gsum,
                float* __restrict__ stops)
{
    __shared__ float lm[4], ls[4];
    __shared__ int lastflag;
    int g = blockIdx.y;
    float m = -3.0e38f, s = 0.f;
    for (int n = blockIdx.x * 256 + threadIdx.x; n < NNODES; n += gridDim.x * 256) {
        if (masks[(size_t)g * NNODES + n]) {
            float v = scores[n];
            if (v > m) { s = s * __expf(m - v) + 1.f; m = v; }
            else s += __expf(v - m);
        }
    }
#pragma unroll
    for (int o = 1; o < 64; o <<= 1) {
        float om = __shfl_xor(m, o), os = __shfl_xor(s, o);
        float M = fmaxf(m, om);
        s = s * __expf(m - M) + os * __expf(om - M);
        m = M;
    }
    if ((threadIdx.x & 63) == 0) { lm[threadIdx.x >> 6] = m; ls[threadIdx.x >> 6] = s; }
    __syncthreads();
    if (threadIdx.x == 0) {
        float M = m, S = s;
        for (int w_ = 1; w_ < 4; w_++) {
            float M2 = fmaxf(M, lm[w_]);
            S = S * __expf(M - M2) + ls[w_] * __expf(lm[w_] - M2);
            M = M2;
        }
        pmax[g * 64 + blockIdx.x] = M;
        psum[g * 64 + blockIdx.x] = S;
        __threadfence();                         // make partials device-visible
        int old = atomicAdd(&pcnt[g], 1);
        lastflag = (old == 63);
    }
    __syncthreads();
    if (!lastflag) return;

    // last block for this graph: merge partials + ctx pooling + stop score
    int tid = threadIdx.x;
    if (tid < 64) {
        int cnt = cur_counts[g];
        float cs = 0.f;
        for (int k = 0; k < KCUR; k++)
            if (k < cnt) cs += hf[(size_t)cur_nodes[g * KCUR + k] * HIDN + tid];
        float ctx = cs / (float)(cnt > 1 ? cnt : 1);
        float p = ctx * sw[tid];
#pragma unroll
        for (int o = 1; o < 64; o <<= 1) p += __shfl_xor(p, o);
        float stop = tanhf(p + sb[0]);

        float mm = pmax[g * 64 + tid], sm = psum[g * 64 + tid];
#pragma unroll
        for (int o = 1; o < 64; o <<= 1) {
            float om = __shfl_xor(mm, o), os = __shfl_xor(sm, o);
            float M = fmaxf(mm, om);
            sm = sm * __expf(mm - M) + os * __expf(om - M);
            mm = M;
        }
        if (tid == 0) {
            float M2 = fmaxf(mm, stop);
            float S2 = sm * __expf(mm - M2) + __expf(stop - M2);
            gmax[g] = M2; gsum[g] = S2; stops[g] = stop;
        }
    }
}

// ---------------- final probability write ----------------
__global__ __launch_bounds__(256)
void write_k(const float* __restrict__ scores, const int* __restrict__ masks,
             const float* __restrict__ gmax, const float* __restrict__ gsum,
             const float* __restrict__ stops, const int* __restrict__ cur_counts,
             float* __restrict__ out)
{
    int g = blockIdx.y;
    int j = blockIdx.x * 256 + threadIdx.x;
    if (j > NNODES) return;
    float v;
    if (cur_counts[g] == 0) {
        v = (j == NNODES) ? 1.f : 0.f;
    } else {
        float m = gmax[g];
        float Z = gsum[g];
        if (j == NNODES) v = __expf(stops[g] - m) / Z;
        else v = masks[(size_t)g * NNODES + j] ? __expf(scores[j] - m) / Z : 0.f;
    }
    out[(size_t)g * (NNODES + 1) + j] = v;
}

extern "C" void kernel_launch(void* const* d_in, const int* in_sizes, int n_in,
                              void* d_out, int out_size, void* d_ws, size_t ws_size,
                              hipStream_t stream) {
    const float* x        = (const float*)d_in[0];
    const int* ei         = (const int*)d_in[1];
    const int* cur_nodes  = (const int*)d_in[2];
    const int* cur_counts = (const int*)d_in[3];
    const int* masks      = (const int*)d_in[4];
    const float* W1       = (const float*)d_in[5];
    const float* att_s1   = (const float*)d_in[6];
    const float* att_d1   = (const float*)d_in[7];
    const float* b1       = (const float*)d_in[8];
    const float* W2       = (const float*)d_in[9];
    const float* att_s2   = (const float*)d_in[10];
    const float* att_d2   = (const float*)d_in[11];
    const float* b2       = (const float*)d_in[12];
    const float* action_w = (const float*)d_in[13];
    const float* action_b = (const float*)d_in[14];
    const float* stop_w   = (const float*)d_in[15];
    const float* stop_b   = (const float*)d_in[16];
    float* out = (float*)d_out;

    const int* srcp = ei;
    const int* dstp = ei + NEDGES;

    // ---- workspace layout ----
    int* deg  = (int*)d_ws;                                  // 50000 (zeroed)
    int* pcnt = deg + NNODES;                                // 32 (zeroed)
    char* zend = (char*)(pcnt + GG);
    size_t zbytes = zend - (char*)d_ws;
    int* rowptr = (int*)zend;                                // 50001 (+3 pad)
    int* cursor = rowptr + NNODES + 4;                       // 50000
    int* csr    = cursor + NNODES;                           // 800000
    u16* W1p    = (u16*)(csr + NEDGES);                      // 32768
    u16* W2p    = W1p + 32768;                               // 16384
    u8*  h1f8   = (u8*)(W2p + 16384);                        // N*256
    u8*  h2f8   = h1f8 + (size_t)NNODES * F1;                // N*64
    float* as1  = (float*)(h2f8 + (size_t)NNODES * HIDN);    // N*4
    float* ad1  = as1 + (size_t)NNODES * 4;                  // N*4
    float* as2  = ad1 + (size_t)NNODES * 4;                  // N
    float* ad2  = as2 + NNODES;                              // N
    float* hf   = ad2 + NNODES;                              // N*64
    float* scores = hf + (size_t)NNODES * HIDN;              // N
    float* stops  = scores + NNODES;                         // G
    float* pmax = stops + GG;                                // G*64
    float* psum = pmax + GG * 64;                            // G*64
    float* gmax = psum + GG * 64;                            // G
    float* gsum = gmax + GG;                                 // G
    size_t total = (char*)(gsum + GG) - (char*)d_ws;
    if (total > ws_size) return;

    auto cdiv = [](long long a, long long b) { return (int)((a + b - 1) / b); };

    (void)hipMemsetAsync(deg, 0, zbytes, stream);

    hist_pack_k<<<HBLK + 192, 256, 0, stream>>>(dstp, deg, W1, W2, W1p, W2p);
    expand_k<<<NCHUNK, 256, 0, stream>>>(deg, rowptr, cursor);
    scat_gemm1_k<<<HBLK + GBLK, 256, 0, stream>>>(srcp, dstp, cursor, csr,
                                                  x, W1p, att_s1, att_d1, h1f8, as1, ad1);
    gagg1_k<<<NNODES / 16, 256, 0, stream>>>(rowptr, csr, as1, ad1, h1f8, b1,
                                             W2p, att_s2, att_d2, h2f8, as2, ad2);
    gagg2<<<cdiv(NNODES, 4), 256, 0, stream>>>(rowptr, csr, as2, ad2, h2f8, b2,
                                               action_w, action_b, hf, scores);
    partials_k<<<dim3(64, GG), 256, 0, stream>>>(scores, masks, hf, cur_nodes, cur_counts,
                                                 stop_w, stop_b, pmax, psum, pcnt,
                                                 gmax, gsum, stops);
    write_k<<<dim3(cdiv(NNODES + 1, 256), GG), 256, 0, stream>>>(scores, masks, gmax, gsum,
                                                                 stops, cur_counts, out);
}

// Round 9
// 390.123 us; speedup vs baseline: 1.0011x; 1.0011x over previous
//
#include <hip/hip_runtime.h>
#include <hip/hip_runtime_api.h>

#define NNODES 50000
#define NEDGES 800000
#define GG 32
#define KCUR 16
#define FIN 128
#define HIDN 64
#define NHEADS 4
#define F1 256          // NHEADS*HIDN
#define NCHUNK 196      // ceil(NNODES/256)
#define HBLK 3125       // NEDGES/256

typedef unsigned short u16;
typedef unsigned char u8;
typedef short bf8 __attribute__((ext_vector_type(8)));    // 8 bf16 in 4 VGPRs
typedef float f32x4 __attribute__((ext_vector_type(4)));

// ---- bf16 helpers ----
__device__ __forceinline__ u16 f2bf(float f) {
    unsigned u = __float_as_uint(f);
    return (u16)((u + 0x7fffu + ((u >> 16) & 1u)) >> 16);   // RNE
}
__device__ __forceinline__ float lrelu(float x) { return x > 0.f ? x : 0.2f * x; }
// fp8 e4m3 HW converts
__device__ __forceinline__ unsigned pk4fp8(float a, float b, float c, float d) {
    unsigned u = __builtin_amdgcn_cvt_pk_fp8_f32(a, b, 0u, false);
    u = __builtin_amdgcn_cvt_pk_fp8_f32(c, d, u, true);
    return u;
}
template<int SEL>
__device__ __forceinline__ float fp8f(unsigned v) {
    return __builtin_amdgcn_cvt_f32_fp8(v, SEL);   // SEL compile-time const
}
__device__ __forceinline__ void acc16(float ex, uint4 v, float* acc) {
    acc[0]  = fmaf(ex, fp8f<0>(v.x), acc[0]);
    acc[1]  = fmaf(ex, fp8f<1>(v.x), acc[1]);
    acc[2]  = fmaf(ex, fp8f<2>(v.x), acc[2]);
    acc[3]  = fmaf(ex, fp8f<3>(v.x), acc[3]);
    acc[4]  = fmaf(ex, fp8f<0>(v.y), acc[4]);
    acc[5]  = fmaf(ex, fp8f<1>(v.y), acc[5]);
    acc[6]  = fmaf(ex, fp8f<2>(v.y), acc[6]);
    acc[7]  = fmaf(ex, fp8f<3>(v.y), acc[7]);
    acc[8]  = fmaf(ex, fp8f<0>(v.z), acc[8]);
    acc[9]  = fmaf(ex, fp8f<1>(v.z), acc[9]);
    acc[10] = fmaf(ex, fp8f<2>(v.z), acc[10]);
    acc[11] = fmaf(ex, fp8f<3>(v.z), acc[11]);
    acc[12] = fmaf(ex, fp8f<0>(v.w), acc[12]);
    acc[13] = fmaf(ex, fp8f<1>(v.w), acc[13]);
    acc[14] = fmaf(ex, fp8f<2>(v.w), acc[14]);
    acc[15] = fmaf(ex, fp8f<3>(v.w), acc[15]);
}
__device__ __forceinline__ void acc8(float ex, uint2 v, float* acc) {
    acc[0] = fmaf(ex, fp8f<0>(v.x), acc[0]);
    acc[1] = fmaf(ex, fp8f<1>(v.x), acc[1]);
    acc[2] = fmaf(ex, fp8f<2>(v.x), acc[2]);
    acc[3] = fmaf(ex, fp8f<3>(v.x), acc[3]);
    acc[4] = fmaf(ex, fp8f<0>(v.y), acc[4]);
    acc[5] = fmaf(ex, fp8f<1>(v.y), acc[5]);
    acc[6] = fmaf(ex, fp8f<2>(v.y), acc[6]);
    acc[7] = fmaf(ex, fp8f<3>(v.y), acc[7]);
}

// ---------------- fused: edge histogram + weight pack (both low-VGPR) ---------
__global__ __launch_bounds__(256)
void hist_pack_k(const int* __restrict__ dst, int* __restrict__ deg,
                 const float* __restrict__ W1, const float* __restrict__ W2,
                 u16* __restrict__ W1p, u16* __restrict__ W2p)
{
    if (blockIdx.x < HBLK) {
        int e = blockIdx.x * 256 + threadIdx.x;
        if (e < NEDGES) atomicAdd(&deg[dst[e]], 1);
        return;
    }
    int idx = (blockIdx.x - HBLK) * 256 + threadIdx.x;
    const float* src; u16* dstp; int S, N, li;
    if (idx < 32768) { src = W1; dstp = W1p; S = FIN / 32; N = F1; li = idx; }
    else if (idx < 49152) { src = W2; dstp = W2p; S = F1 / 32; N = HIDN; li = idx - 32768; }
    else return;
    int j = li & 7, l = (li >> 3) & 63, rest = li >> 9;
    int s = rest % S, t = rest / S;
    int k = s * 32 + (l >> 4) * 8 + j;
    int n = t * 16 + (l & 15);
    dstp[li] = f2bf(src[(size_t)k * N + n]);
}

// ---------------- expand: rowptr/cursor; block offset self-computed ----------
__global__ __launch_bounds__(256)
void expand_k(const int* __restrict__ deg, int* __restrict__ rowptr,
              int* __restrict__ cursor)
{
    __shared__ int ws[4], ws2[4];
    __shared__ int boffs;
    int tid = threadIdx.x, lane = tid & 63, wid = tid >> 6;
    int v0 = 0;
    for (int b = 0; b < (int)blockIdx.x; b++) v0 += deg[b * 256 + tid];
#pragma unroll
    for (int o = 32; o; o >>= 1) v0 += __shfl_down(v0, o);
    if (lane == 0) ws[wid] = v0;
    __syncthreads();
    if (tid == 0) boffs = ws[0] + ws[1] + ws[2] + ws[3];
    __syncthreads();
    int i = blockIdx.x * 256 + tid;
    int v = (i < NNODES) ? deg[i] : 0;
    int x = v;
#pragma unroll
    for (int o = 1; o < 64; o <<= 1) {
        int y = __shfl_up(x, o);
        if (lane >= o) x += y;
    }
    if (lane == 63) ws2[wid] = x;
    __syncthreads();
    int off = boffs;
    for (int w = 0; w < wid; w++) off += ws2[w];
    int excl = off + x - v;
    if (i < NNODES) { rowptr[i] = excl; cursor[i] = excl; }
    if (i == 0) rowptr[NNODES] = NEDGES;
}

// ---------------- CSR scatter (standalone: low VGPR, max occupancy) ----------
__global__ __launch_bounds__(256)
void scatter_k(const int* __restrict__ src, const int* __restrict__ dst,
               int* __restrict__ cursor, int* __restrict__ csr)
{
    int e = blockIdx.x * 256 + threadIdx.x;
    if (e >= NEDGES) return;
    int d = dst[e];
    int pos = atomicAdd(&cursor[d], 1);
    csr[pos] = src[e];
}

// ---------------- GEMM1: h1 = x @ W1 (fp32 in, fp8 out) + fused att dots ------
__global__ __launch_bounds__(256)
void gemm1_k(const float* __restrict__ X, const u16* __restrict__ Bp,
             const float* __restrict__ att_s, const float* __restrict__ att_d,
             u8* __restrict__ h1f8, float* __restrict__ as1, float* __restrict__ ad1)
{
    const int S = FIN / 32;  // 4
    int lane = threadIdx.x & 63, w = threadIdx.x >> 6;
    int m0 = blockIdx.x * 64;
    int row_in = lane & 15, kq = lane >> 4;
    f32x4 acc[4][4];
#pragma unroll
    for (int r = 0; r < 4; r++)
#pragma unroll
        for (int tt = 0; tt < 4; tt++) acc[r][tt] = (f32x4){0.f, 0.f, 0.f, 0.f};
    int R = (NNODES - m0) >> 4; if (R > 4) R = 4;

    for (int s = 0; s < S; s++) {
        bf8 bfrag[4];
#pragma unroll
        for (int tt = 0; tt < 4; tt++) {
            int t = w * 4 + tt;
            bfrag[tt] = *(const bf8*)(Bp + (((size_t)t * S + s) * 64 + lane) * 8);
        }
        int kb = s * 32 + kq * 8;
        bf8 af[4];
#pragma unroll
        for (int r = 0; r < 4; r++)
            if (r < R) {
                const float* xp = X + (size_t)(m0 + r * 16 + row_in) * FIN + kb;
                float4 x0 = *(const float4*)xp;
                float4 x1 = *(const float4*)(xp + 4);
                bf8 a;
                a[0] = (short)f2bf(x0.x); a[1] = (short)f2bf(x0.y);
                a[2] = (short)f2bf(x0.z); a[3] = (short)f2bf(x0.w);
                a[4] = (short)f2bf(x1.x); a[5] = (short)f2bf(x1.y);
                a[6] = (short)f2bf(x1.z); a[7] = (short)f2bf(x1.w);
                af[r] = a;
            }
#pragma unroll
        for (int r = 0; r < 4; r++)
            if (r < R)
#pragma unroll
                for (int tt = 0; tt < 4; tt++)
                    acc[r][tt] = __builtin_amdgcn_mfma_f32_16x16x32_bf16(bfrag[tt], af[r], acc[r][tt], 0, 0, 0);
    }
    float attS[16], attD[16];
#pragma unroll
    for (int tt = 0; tt < 4; tt++)
#pragma unroll
        for (int v = 0; v < 4; v++) {
            attS[tt * 4 + v] = att_s[w * 64 + tt * 16 + kq * 4 + v];
            attD[tt * 4 + v] = att_d[w * 64 + tt * 16 + kq * 4 + v];
        }
#pragma unroll
    for (int r = 0; r < 4; r++) {
        if (r >= R) break;
        int node = m0 + r * 16 + row_in;
        float pa = 0.f, pd = 0.f;
#pragma unroll
        for (int tt = 0; tt < 4; tt++) {
            unsigned u = pk4fp8(acc[r][tt][0], acc[r][tt][1], acc[r][tt][2], acc[r][tt][3]);
            *(unsigned*)(h1f8 + (size_t)node * F1 + (w * 4 + tt) * 16 + kq * 4) = u;
#pragma unroll
            for (int v = 0; v < 4; v++) {
                pa = fmaf(acc[r][tt][v], attS[tt * 4 + v], pa);
                pd = fmaf(acc[r][tt][v], attD[tt * 4 + v], pd);
            }
        }
        pa += __shfl_xor(pa, 16); pa += __shfl_xor(pa, 32);
        pd += __shfl_xor(pd, 16); pd += __shfl_xor(pd, 32);
        if (kq == 0) { as1[node * 4 + w] = pa; ad1[node * 4 + w] = pd; }
    }
}

// ---------------- layer-1 gather: 16 lanes/edge, 4 edges in flight, 2x unroll --
// lane -> 16 fp8 channels (c0 = (lane&15)*16, head = (lane&15)>>2); quarter
// q = lane>>4 strides edges by 4. Virtual edge p=0 = self loop. bf16 out.
__global__ __launch_bounds__(256)
void gagg1(const int* __restrict__ rowptr, const int* __restrict__ csr,
           const float* __restrict__ as1, const float* __restrict__ ad1,
           const u8* __restrict__ h1f8, const float* __restrict__ b1,
           u16* __restrict__ outp)
{
    int wid = threadIdx.x >> 6, lane = threadIdx.x & 63;
    int d = blockIdx.x * 4 + wid;
    if (d >= NNODES) return;
    int beg = rowptr[d];
    int tot = rowptr[d + 1] - beg + 1;     // + self loop
    int q = lane >> 4;
    int l16 = lane & 15;
    int h = l16 >> 2;
    int c0 = l16 << 4;
    float adh = ad1[d * 4 + h];
    float den = 0.f;
    float acc[16];
#pragma unroll
    for (int j = 0; j < 16; j++) acc[j] = 0.f;

    const u8* hbase = h1f8 + c0;
    int p = q;
    for (; p + 4 < tot; p += 8) {          // 2 independent chains per iter
        int s0 = (p == 0) ? d : csr[beg + p - 1];
        int s1 = csr[beg + p + 3];
        uint4 v0 = *(const uint4*)(hbase + (size_t)s0 * F1);
        uint4 v1 = *(const uint4*)(hbase + (size_t)s1 * F1);
        float e0 = __expf(lrelu(as1[s0 * 4 + h] + adh));
        float e1 = __expf(lrelu(as1[s1 * 4 + h] + adh));
        den += e0 + e1;
        acc16(e0, v0, acc);
        acc16(e1, v1, acc);
    }
    for (; p < tot; p += 4) {
        int s = (p == 0) ? d : csr[beg + p - 1];
        uint4 v = *(const uint4*)(hbase + (size_t)s * F1);
        float ex = __expf(lrelu(as1[s * 4 + h] + adh));
        den += ex;
        acc16(ex, v, acc);
    }
    den += __shfl_xor(den, 16); den += __shfl_xor(den, 32);
#pragma unroll
    for (int j = 0; j < 16; j++) {
        acc[j] += __shfl_xor(acc[j], 16);
        acc[j] += __shfl_xor(acc[j], 32);
    }
    if (lane < 16) {
        float rden = 1.f / den;
        bf8 lo, hi;
#pragma unroll
        for (int j = 0; j < 8; j++) {
            lo[j] = (short)f2bf(fmaxf(fmaf(acc[j], rden, b1[c0 + j]), 0.f));
            hi[j] = (short)f2bf(fmaxf(fmaf(acc[8 + j], rden, b1[c0 + 8 + j]), 0.f));
        }
        *(bf8*)(outp + (size_t)d * F1 + c0) = lo;
        *(bf8*)(outp + (size_t)d * F1 + c0 + 8) = hi;
    }
}

// ---------------- GEMM2: h2 = h1r @ W2 (bf16 in, fp8 out) + fused att dots ----
__global__ __launch_bounds__(256)
void gemm2_k(const u16* __restrict__ A, const u16* __restrict__ Bp,
             const float* __restrict__ att_s, const float* __restrict__ att_d,
             u8* __restrict__ h2f8, float* __restrict__ as2, float* __restrict__ ad2)
{
    const int S = F1 / 32;   // 8
    __shared__ float asl[4][64], adl[4][64];
    int lane = threadIdx.x & 63, w = threadIdx.x >> 6;
    int m0 = blockIdx.x * 64;
    int row_in = lane & 15, kq = lane >> 4;
    f32x4 acc[4];
#pragma unroll
    for (int r = 0; r < 4; r++) acc[r] = (f32x4){0.f, 0.f, 0.f, 0.f};
    int R = (NNODES - m0) >> 4; if (R > 4) R = 4;

    for (int s = 0; s < S; s++) {
        bf8 bfrag = *(const bf8*)(Bp + (((size_t)w * S + s) * 64 + lane) * 8);
        int kb = s * 32 + kq * 8;
        bf8 af[4];
#pragma unroll
        for (int r = 0; r < 4; r++)
            if (r < R) af[r] = *(const bf8*)(A + (size_t)(m0 + r * 16 + row_in) * F1 + kb);
#pragma unroll
        for (int r = 0; r < 4; r++)
            if (r < R)
                acc[r] = __builtin_amdgcn_mfma_f32_16x16x32_bf16(bfrag, af[r], acc[r], 0, 0, 0);
    }
    float attS[4], attD[4];
#pragma unroll
    for (int v = 0; v < 4; v++) {
        attS[v] = att_s[w * 16 + kq * 4 + v];
        attD[v] = att_d[w * 16 + kq * 4 + v];
    }
#pragma unroll
    for (int r = 0; r < 4; r++) {
        if (r >= R) break;
        int node = m0 + r * 16 + row_in;
        unsigned u = pk4fp8(acc[r][0], acc[r][1], acc[r][2], acc[r][3]);
        *(unsigned*)(h2f8 + (size_t)node * HIDN + w * 16 + kq * 4) = u;
        float pa = 0.f, pd = 0.f;
#pragma unroll
        for (int v = 0; v < 4; v++) {
            pa = fmaf(acc[r][v], attS[v], pa);
            pd = fmaf(acc[r][v], attD[v], pd);
        }
        pa += __shfl_xor(pa, 16); pa += __shfl_xor(pa, 32);
        pd += __shfl_xor(pd, 16); pd += __shfl_xor(pd, 32);
        if (kq == 0) { asl[w][r * 16 + row_in] = pa; adl[w][r * 16 + row_in] = pd; }
    }
    __syncthreads();
    int tid = threadIdx.x;
    if (tid < R * 16) {
        as2[m0 + tid] = asl[0][tid] + asl[1][tid] + asl[2][tid] + asl[3][tid];
        ad2[m0 + tid] = adl[0][tid] + adl[1][tid] + adl[2][tid] + adl[3][tid];
    }
}

// ---------------- layer-2 gather: 8 lanes/edge, 8 edges in flight, 2x unroll ---
__global__ __launch_bounds__(256)
void gagg2(const int* __restrict__ rowptr, const int* __restrict__ csr,
           const float* __restrict__ as2, const float* __restrict__ ad2,
           const u8* __restrict__ h2f8, const float* __restrict__ b2,
           const float* __restrict__ aw, const float* __restrict__ ab,
           float* __restrict__ outp, float* __restrict__ scores)
{
    int wid = threadIdx.x >> 6, lane = threadIdx.x & 63;
    int d = blockIdx.x * 4 + wid;
    if (d >= NNODES) return;
    int beg = rowptr[d];
    int tot = rowptr[d + 1] - beg + 1;
    int oct = lane >> 3;
    int l8 = lane & 7;
    int c0 = l8 << 3;
    float ads = ad2[d];
    float den = 0.f;
    float acc[8];
#pragma unroll
    for (int j = 0; j < 8; j++) acc[j] = 0.f;

    const u8* hbase = h2f8 + c0;
    int p = oct;
    for (; p + 8 < tot; p += 16) {
        int s0 = (p == 0) ? d : csr[beg + p - 1];
        int s1 = csr[beg + p + 7];
        uint2 v0 = *(const uint2*)(hbase + (size_t)s0 * HIDN);
        uint2 v1 = *(const uint2*)(hbase + (size_t)s1 * HIDN);
        float e0 = __expf(lrelu(as2[s0] + ads));
        float e1 = __expf(lrelu(as2[s1] + ads));
        den += e0 + e1;
        acc8(e0, v0, acc);
        acc8(e1, v1, acc);
    }
    for (; p < tot; p += 8) {
        int s = (p == 0) ? d : csr[beg + p - 1];
        uint2 v = *(const uint2*)(hbase + (size_t)s * HIDN);
        float ex = __expf(lrelu(as2[s] + ads));
        den += ex;
        acc8(ex, v, acc);
    }
    den += __shfl_xor(den, 8); den += __shfl_xor(den, 16); den += __shfl_xor(den, 32);
#pragma unroll
    for (int j = 0; j < 8; j++) {
        acc[j] += __shfl_xor(acc[j], 8);
        acc[j] += __shfl_xor(acc[j], 16);
        acc[j] += __shfl_xor(acc[j], 32);
    }
    float rden = 1.f / den;
    float o[8];
#pragma unroll
    for (int j = 0; j < 8; j++) o[j] = fmaf(acc[j], rden, b2[c0 + j]);
    if (lane < 8) {
        float4 lo = make_float4(o[0], o[1], o[2], o[3]);
        float4 hi = make_float4(o[4], o[5], o[6], o[7]);
        *(float4*)(outp + (size_t)d * HIDN + c0) = lo;
        *(float4*)(outp + (size_t)d * HIDN + c0 + 4) = hi;
    }
    float p_ = 0.f;
#pragma unroll
    for (int j = 0; j < 8; j++) p_ = fmaf(o[j], aw[c0 + j], p_);
    p_ += __shfl_xor(p_, 1); p_ += __shfl_xor(p_, 2); p_ += __shfl_xor(p_, 4);
    if (lane == 0) scores[d] = tanhf(p_ + ab[0]);
}

// ---------------- masked online-softmax partials + last-block combine ---------
__global__ __launch_bounds__(256)
void partials_k(const float* __restrict__ scores, const int* __restrict__ masks,
                const float* __restrict__ hf, const int* __restrict__ cur_nodes,
                const int* __restrict__ cur_counts, const float* __restrict__ sw,
                const float* __restrict__ sb,
                float* __restrict__ pmax, float* __restrict__ psum,
                int* __restrict__ pcnt,
                float* __restrict__ gmax, float* __restrict__ gsum,
                float* __restrict__ stops)
{
    __shared__ float lm[4], ls[4];
    __shared__ int lastflag;
    int g = blockIdx.y;
    float m = -3.0e38f, s = 0.f;
    for (int n = blockIdx.x * 256 + threadIdx.x; n < NNODES; n += gridDim.x * 256) {
        if (masks[(size_t)g * NNODES + n]) {
            float v = scores[n];
            if (v > m) { s = s * __expf(m - v) + 1.f; m = v; }
            else s += __expf(v - m);
        }
    }
#pragma unroll
    for (int o = 1; o < 64; o <<= 1) {
        float om = __shfl_xor(m, o), os = __shfl_xor(s, o);
        float M = fmaxf(m, om);
        s = s * __expf(m - M) + os * __expf(om - M);
        m = M;
    }
    if ((threadIdx.x & 63) == 0) { lm[threadIdx.x >> 6] = m; ls[threadIdx.x >> 6] = s; }
    __syncthreads();
    if (threadIdx.x == 0) {
        float M = m, S = s;
        for (int w_ = 1; w_ < 4; w_++) {
            float M2 = fmaxf(M, lm[w_]);
            S = S * __expf(M - M2) + ls[w_] * __expf(lm[w_] - M2);
            M = M2;
        }
        pmax[g * 64 + blockIdx.x] = M;
        psum[g * 64 + blockIdx.x] = S;
        __threadfence();
        int old = atomicAdd(&pcnt[g], 1);
        lastflag = (old == 63);
    }
    __syncthreads();
    if (!lastflag) return;

    int tid = threadIdx.x;
    if (tid < 64) {
        int cnt = cur_counts[g];
        float cs = 0.f;
        for (int k = 0; k < KCUR; k++)
            if (k < cnt) cs += hf[(size_t)cur_nodes[g * KCUR + k] * HIDN + tid];
        float ctx = cs / (float)(cnt > 1 ? cnt : 1);
        float p = ctx * sw[tid];
#pragma unroll
        for (int o = 1; o < 64; o <<= 1) p += __shfl_xor(p, o);
        float stop = tanhf(p + sb[0]);

        float mm = pmax[g * 64 + tid], sm = psum[g * 64 + tid];
#pragma unroll
        for (int o = 1; o < 64; o <<= 1) {
            float om = __shfl_xor(mm, o), os = __shfl_xor(sm, o);
            float M = fmaxf(mm, om);
            sm = sm * __expf(mm - M) + os * __expf(om - M);
            mm = M;
        }
        if (tid == 0) {
            float M2 = fmaxf(mm, stop);
            float S2 = sm * __expf(mm - M2) + __expf(stop - M2);
            gmax[g] = M2; gsum[g] = S2; stops[g] = stop;
        }
    }
}

// ---------------- final probability write ----------------
__global__ __launch_bounds__(256)
void write_k(const float* __restrict__ scores, const int* __restrict__ masks,
             const float* __restrict__ gmax, const float* __restrict__ gsum,
             const float* __restrict__ stops, const int* __restrict__ cur_counts,
             float* __restrict__ out)
{
    int g = blockIdx.y;
    int j = blockIdx.x * 256 + threadIdx.x;
    if (j > NNODES) return;
    float v;
    if (cur_counts[g] == 0) {
        v = (j == NNODES) ? 1.f : 0.f;
    } else {
        float m = gmax[g];
        float Z = gsum[g];
        if (j == NNODES) v = __expf(stops[g] - m) / Z;
        else v = masks[(size_t)g * NNODES + j] ? __expf(scores[j] - m) / Z : 0.f;
    }
    out[(size_t)g * (NNODES + 1) + j] = v;
}

extern "C" void kernel_launch(void* const* d_in, const int* in_sizes, int n_in,
                              void* d_out, int out_size, void* d_ws, size_t ws_size,
                              hipStream_t stream) {
    const float* x        = (const float*)d_in[0];
    const int* ei         = (const int*)d_in[1];
    const int* cur_nodes  = (const int*)d_in[2];
    const int* cur_counts = (const int*)d_in[3];
    const int* masks      = (const int*)d_in[4];
    const float* W1       = (const float*)d_in[5];
    const float* att_s1   = (const float*)d_in[6];
    const float* att_d1   = (const float*)d_in[7];
    const float* b1       = (const float*)d_in[8];
    const float* W2       = (const float*)d_in[9];
    const float* att_s2   = (const float*)d_in[10];
    const float* att_d2   = (const float*)d_in[11];
    const float* b2       = (const float*)d_in[12];
    const float* action_w = (const float*)d_in[13];
    const float* action_b = (const float*)d_in[14];
    const float* stop_w   = (const float*)d_in[15];
    const float* stop_b   = (const float*)d_in[16];
    float* out = (float*)d_out;

    const int* srcp = ei;
    const int* dstp = ei + NEDGES;

    // ---- workspace layout ----
    int* deg  = (int*)d_ws;                                  // 50000 (zeroed)
    int* pcnt = deg + NNODES;                                // 32 (zeroed)
    char* zend = (char*)(pcnt + GG);
    size_t zbytes = zend - (char*)d_ws;
    int* rowptr = (int*)zend;                                // 50001 (+3 pad)
    int* cursor = rowptr + NNODES + 4;                       // 50000
    int* csr    = cursor + NNODES;                           // 800000
    u16* W1p    = (u16*)(csr + NEDGES);                      // 32768
    u16* W2p    = W1p + 32768;                               // 16384
    u8*  h1f8   = (u8*)(W2p + 16384);                        // N*256
    u16* h1rb   = (u16*)(h1f8 + (size_t)NNODES * F1);        // N*256 bf16
    u8*  h2f8   = (u8*)(h1rb + (size_t)NNODES * F1);         // N*64
    float* as1  = (float*)(h2f8 + (size_t)NNODES * HIDN);    // N*4
    float* ad1  = as1 + (size_t)NNODES * 4;                  // N*4
    float* as2  = ad1 + (size_t)NNODES * 4;                  // N
    float* ad2  = as2 + NNODES;                              // N
    float* hf   = ad2 + NNODES;                              // N*64
    float* scores = hf + (size_t)NNODES * HIDN;              // N
    float* stops  = scores + NNODES;                         // G
    float* pmax = stops + GG;                                // G*64
    float* psum = pmax + GG * 64;                            // G*64
    float* gmax = psum + GG * 64;                            // G
    float* gsum = gmax + GG;                                 // G
    size_t total = (char*)(gsum + GG) - (char*)d_ws;
    if (total > ws_size) return;

    auto cdiv = [](long long a, long long b) { return (int)((a + b - 1) / b); };

    (void)hipMemsetAsync(deg, 0, zbytes, stream);

    hist_pack_k<<<HBLK + 192, 256, 0, stream>>>(dstp, deg, W1, W2, W1p, W2p);
    expand_k<<<NCHUNK, 256, 0, stream>>>(deg, rowptr, cursor);
    scatter_k<<<HBLK, 256, 0, stream>>>(srcp, dstp, cursor, csr);
    gemm1_k<<<cdiv(NNODES, 64), 256, 0, stream>>>(x, W1p, att_s1, att_d1, h1f8, as1, ad1);
    gagg1<<<cdiv(NNODES, 4), 256, 0, stream>>>(rowptr, csr, as1, ad1, h1f8, b1, h1rb);
    gemm2_k<<<cdiv(NNODES, 64), 256, 0, stream>>>(h1rb, W2p, att_s2, att_d2, h2f8, as2, ad2);
    gagg2<<<cdiv(NNODES, 4), 256, 0, stream>>>(rowptr, csr, as2, ad2, h2f8, b2,
                                               action_w, action_b, hf, scores);
    partials_k<<<dim3(64, GG), 256, 0, stream>>>(scores, masks, hf, cur_nodes, cur_counts,
                                                 stop_w, stop_b, pmax, psum, pcnt,
                                                 gmax, gsum, stops);
    write_k<<<dim3(cdiv(NNODES + 1, 256), GG), 256, 0, stream>>>(scores, masks, gmax, gsum,
                                                                 stops, cur_counts, out);
}

// Round 10
// 371.006 us; speedup vs baseline: 1.0527x; 1.0515x over previous
//
#include <hip/hip_runtime.h>
#include <hip/hip_runtime_api.h>

#define NNODES 50000
#define NEDGES 800000
#define GG 32
#define KCUR 16
#define FIN 128
#define HIDN 64
#define NHEADS 4
#define F1 256          // NHEADS*HIDN
#define NCHUNK 196      // ceil(NNODES/256)
#define HBLK 3125       // NEDGES/256

typedef unsigned short u16;
typedef unsigned char u8;
typedef short bf8 __attribute__((ext_vector_type(8)));    // 8 bf16 in 4 VGPRs
typedef float f32x4 __attribute__((ext_vector_type(4)));

// ---- bf16 helpers ----
__device__ __forceinline__ u16 f2bf(float f) {
    unsigned u = __float_as_uint(f);
    return (u16)((u + 0x7fffu + ((u >> 16) & 1u)) >> 16);   // RNE
}
__device__ __forceinline__ float lrelu(float x) { return x > 0.f ? x : 0.2f * x; }
// fp8 e4m3 HW converts
__device__ __forceinline__ unsigned pk4fp8(float a, float b, float c, float d) {
    unsigned u = __builtin_amdgcn_cvt_pk_fp8_f32(a, b, 0u, false);
    u = __builtin_amdgcn_cvt_pk_fp8_f32(c, d, u, true);
    return u;
}
template<int SEL>
__device__ __forceinline__ float fp8f(unsigned v) {
    return __builtin_amdgcn_cvt_f32_fp8(v, SEL);   // SEL compile-time const
}
__device__ __forceinline__ void acc16(float ex, uint4 v, float* acc) {
    acc[0]  = fmaf(ex, fp8f<0>(v.x), acc[0]);
    acc[1]  = fmaf(ex, fp8f<1>(v.x), acc[1]);
    acc[2]  = fmaf(ex, fp8f<2>(v.x), acc[2]);
    acc[3]  = fmaf(ex, fp8f<3>(v.x), acc[3]);
    acc[4]  = fmaf(ex, fp8f<0>(v.y), acc[4]);
    acc[5]  = fmaf(ex, fp8f<1>(v.y), acc[5]);
    acc[6]  = fmaf(ex, fp8f<2>(v.y), acc[6]);
    acc[7]  = fmaf(ex, fp8f<3>(v.y), acc[7]);
    acc[8]  = fmaf(ex, fp8f<0>(v.z), acc[8]);
    acc[9]  = fmaf(ex, fp8f<1>(v.z), acc[9]);
    acc[10] = fmaf(ex, fp8f<2>(v.z), acc[10]);
    acc[11] = fmaf(ex, fp8f<3>(v.z), acc[11]);
    acc[12] = fmaf(ex, fp8f<0>(v.w), acc[12]);
    acc[13] = fmaf(ex, fp8f<1>(v.w), acc[13]);
    acc[14] = fmaf(ex, fp8f<2>(v.w), acc[14]);
    acc[15] = fmaf(ex, fp8f<3>(v.w), acc[15]);
}
__device__ __forceinline__ void acc8(float ex, uint2 v, float* acc) {
    acc[0] = fmaf(ex, fp8f<0>(v.x), acc[0]);
    acc[1] = fmaf(ex, fp8f<1>(v.x), acc[1]);
    acc[2] = fmaf(ex, fp8f<2>(v.x), acc[2]);
    acc[3] = fmaf(ex, fp8f<3>(v.x), acc[3]);
    acc[4] = fmaf(ex, fp8f<0>(v.y), acc[4]);
    acc[5] = fmaf(ex, fp8f<1>(v.y), acc[5]);
    acc[6] = fmaf(ex, fp8f<2>(v.y), acc[6]);
    acc[7] = fmaf(ex, fp8f<3>(v.y), acc[7]);
}

// ---------------- fused: edge histogram + weight pack (both low-VGPR) ---------
__global__ __launch_bounds__(256)
void hist_pack_k(const int* __restrict__ dst, int* __restrict__ deg,
                 const float* __restrict__ W1, const float* __restrict__ W2,
                 u16* __restrict__ W1p, u16* __restrict__ W2p)
{
    if (blockIdx.x < HBLK) {
        int e = blockIdx.x * 256 + threadIdx.x;
        if (e < NEDGES) atomicAdd(&deg[dst[e]], 1);
        return;
    }
    int idx = (blockIdx.x - HBLK) * 256 + threadIdx.x;
    const float* src; u16* dstp; int S, N, li;
    if (idx < 32768) { src = W1; dstp = W1p; S = FIN / 32; N = F1; li = idx; }
    else if (idx < 49152) { src = W2; dstp = W2p; S = F1 / 32; N = HIDN; li = idx - 32768; }
    else return;
    int j = li & 7, l = (li >> 3) & 63, rest = li >> 9;
    int s = rest % S, t = rest / S;
    int k = s * 32 + (l >> 4) * 8 + j;
    int n = t * 16 + (l & 15);
    dstp[li] = f2bf(src[(size_t)k * N + n]);
}

// ---------------- per-256-chunk sums (validated fast in R4/R7) ----------------
__global__ __launch_bounds__(256)
void chunksum_k(const int* __restrict__ deg, int* __restrict__ csum)
{
    __shared__ int ws[4];
    int i = blockIdx.x * 256 + threadIdx.x;
    int v = (i < NNODES) ? deg[i] : 0;
#pragma unroll
    for (int o = 32; o; o >>= 1) v += __shfl_down(v, o);
    if ((threadIdx.x & 63) == 0) ws[threadIdx.x >> 6] = v;
    __syncthreads();
    if (threadIdx.x == 0) csum[blockIdx.x] = ws[0] + ws[1] + ws[2] + ws[3];
}

// ---------------- expand: block offset from csum (one load/thread) ------------
__global__ __launch_bounds__(256)
void expand_k(const int* __restrict__ deg, const int* __restrict__ csum,
              int* __restrict__ rowptr, int* __restrict__ cursor)
{
    __shared__ int ws[4], ws2[4];
    __shared__ int boffs;
    int tid = threadIdx.x, lane = tid & 63, wid = tid >> 6;
    int v0 = (tid < (int)blockIdx.x) ? csum[tid] : 0;   // blockIdx.x <= 195 < 256
#pragma unroll
    for (int o = 32; o; o >>= 1) v0 += __shfl_down(v0, o);
    if (lane == 0) ws[wid] = v0;
    __syncthreads();
    if (tid == 0) boffs = ws[0] + ws[1] + ws[2] + ws[3];
    __syncthreads();
    int i = blockIdx.x * 256 + tid;
    int v = (i < NNODES) ? deg[i] : 0;
    int x = v;
#pragma unroll
    for (int o = 1; o < 64; o <<= 1) {
        int y = __shfl_up(x, o);
        if (lane >= o) x += y;
    }
    if (lane == 63) ws2[wid] = x;
    __syncthreads();
    int off = boffs;
    for (int w = 0; w < wid; w++) off += ws2[w];
    int excl = off + x - v;
    if (i < NNODES) { rowptr[i] = excl; cursor[i] = excl; }
    if (i == 0) rowptr[NNODES] = NEDGES;
}

// ---------------- CSR scatter (standalone: low VGPR, max occupancy) ----------
__global__ __launch_bounds__(256)
void scatter_k(const int* __restrict__ src, const int* __restrict__ dst,
               int* __restrict__ cursor, int* __restrict__ csr)
{
    int e = blockIdx.x * 256 + threadIdx.x;
    if (e >= NEDGES) return;
    int d = dst[e];
    int pos = atomicAdd(&cursor[d], 1);
    csr[pos] = src[e];
}

// ---------------- GEMM1: h1 = x @ W1 (fp32 in, fp8 out) + fused att dots ------
__global__ __launch_bounds__(256)
void gemm1_k(const float* __restrict__ X, const u16* __restrict__ Bp,
             const float* __restrict__ att_s, const float* __restrict__ att_d,
             u8* __restrict__ h1f8, float* __restrict__ as1, float* __restrict__ ad1)
{
    const int S = FIN / 32;  // 4
    int lane = threadIdx.x & 63, w = threadIdx.x >> 6;
    int m0 = blockIdx.x * 64;
    int row_in = lane & 15, kq = lane >> 4;
    f32x4 acc[4][4];
#pragma unroll
    for (int r = 0; r < 4; r++)
#pragma unroll
        for (int tt = 0; tt < 4; tt++) acc[r][tt] = (f32x4){0.f, 0.f, 0.f, 0.f};
    int R = (NNODES - m0) >> 4; if (R > 4) R = 4;

    for (int s = 0; s < S; s++) {
        bf8 bfrag[4];
#pragma unroll
        for (int tt = 0; tt < 4; tt++) {
            int t = w * 4 + tt;
            bfrag[tt] = *(const bf8*)(Bp + (((size_t)t * S + s) * 64 + lane) * 8);
        }
        int kb = s * 32 + kq * 8;
        bf8 af[4];
#pragma unroll
        for (int r = 0; r < 4; r++)
            if (r < R) {
                const float* xp = X + (size_t)(m0 + r * 16 + row_in) * FIN + kb;
                float4 x0 = *(const float4*)xp;
                float4 x1 = *(const float4*)(xp + 4);
                bf8 a;
                a[0] = (short)f2bf(x0.x); a[1] = (short)f2bf(x0.y);
                a[2] = (short)f2bf(x0.z); a[3] = (short)f2bf(x0.w);
                a[4] = (short)f2bf(x1.x); a[5] = (short)f2bf(x1.y);
                a[6] = (short)f2bf(x1.z); a[7] = (short)f2bf(x1.w);
                af[r] = a;
            }
#pragma unroll
        for (int r = 0; r < 4; r++)
            if (r < R)
#pragma unroll
                for (int tt = 0; tt < 4; tt++)
                    acc[r][tt] = __builtin_amdgcn_mfma_f32_16x16x32_bf16(bfrag[tt], af[r], acc[r][tt], 0, 0, 0);
    }
    float attS[16], attD[16];
#pragma unroll
    for (int tt = 0; tt < 4; tt++)
#pragma unroll
        for (int v = 0; v < 4; v++) {
            attS[tt * 4 + v] = att_s[w * 64 + tt * 16 + kq * 4 + v];
            attD[tt * 4 + v] = att_d[w * 64 + tt * 16 + kq * 4 + v];
        }
#pragma unroll
    for (int r = 0; r < 4; r++) {
        if (r >= R) break;
        int node = m0 + r * 16 + row_in;
        float pa = 0.f, pd = 0.f;
#pragma unroll
        for (int tt = 0; tt < 4; tt++) {
            unsigned u = pk4fp8(acc[r][tt][0], acc[r][tt][1], acc[r][tt][2], acc[r][tt][3]);
            *(unsigned*)(h1f8 + (size_t)node * F1 + (w * 4 + tt) * 16 + kq * 4) = u;
#pragma unroll
            for (int v = 0; v < 4; v++) {
                pa = fmaf(acc[r][tt][v], attS[tt * 4 + v], pa);
                pd = fmaf(acc[r][tt][v], attD[tt * 4 + v], pd);
            }
        }
        pa += __shfl_xor(pa, 16); pa += __shfl_xor(pa, 32);
        pd += __shfl_xor(pd, 16); pd += __shfl_xor(pd, 32);
        if (kq == 0) { as1[node * 4 + w] = pa; ad1[node * 4 + w] = pd; }
    }
}

// ---------------- layer-1 gather: 16 lanes/edge, 4 edges in flight, 2x unroll --
__global__ __launch_bounds__(256)
void gagg1(const int* __restrict__ rowptr, const int* __restrict__ csr,
           const float* __restrict__ as1, const float* __restrict__ ad1,
           const u8* __restrict__ h1f8, const float* __restrict__ b1,
           u16* __restrict__ outp)
{
    int wid = threadIdx.x >> 6, lane = threadIdx.x & 63;
    int d = blockIdx.x * 4 + wid;
    if (d >= NNODES) return;
    int beg = rowptr[d];
    int tot = rowptr[d + 1] - beg + 1;     // + self loop
    int q = lane >> 4;
    int l16 = lane & 15;
    int h = l16 >> 2;
    int c0 = l16 << 4;
    float adh = ad1[d * 4 + h];
    float den = 0.f;
    float acc[16];
#pragma unroll
    for (int j = 0; j < 16; j++) acc[j] = 0.f;

    const u8* hbase = h1f8 + c0;
    int p = q;
    for (; p + 4 < tot; p += 8) {          // 2 independent chains per iter
        int s0 = (p == 0) ? d : csr[beg + p - 1];
        int s1 = csr[beg + p + 3];
        uint4 v0 = *(const uint4*)(hbase + (size_t)s0 * F1);
        uint4 v1 = *(const uint4*)(hbase + (size_t)s1 * F1);
        float e0 = __expf(lrelu(as1[s0 * 4 + h] + adh));
        float e1 = __expf(lrelu(as1[s1 * 4 + h] + adh));
        den += e0 + e1;
        acc16(e0, v0, acc);
        acc16(e1, v1, acc);
    }
    for (; p < tot; p += 4) {
        int s = (p == 0) ? d : csr[beg + p - 1];
        uint4 v = *(const uint4*)(hbase + (size_t)s * F1);
        float ex = __expf(lrelu(as1[s * 4 + h] + adh));
        den += ex;
        acc16(ex, v, acc);
    }
    den += __shfl_xor(den, 16); den += __shfl_xor(den, 32);
#pragma unroll
    for (int j = 0; j < 16; j++) {
        acc[j] += __shfl_xor(acc[j], 16);
        acc[j] += __shfl_xor(acc[j], 32);
    }
    if (lane < 16) {
        float rden = 1.f / den;
        bf8 lo, hi;
#pragma unroll
        for (int j = 0; j < 8; j++) {
            lo[j] = (short)f2bf(fmaxf(fmaf(acc[j], rden, b1[c0 + j]), 0.f));
            hi[j] = (short)f2bf(fmaxf(fmaf(acc[8 + j], rden, b1[c0 + 8 + j]), 0.f));
        }
        *(bf8*)(outp + (size_t)d * F1 + c0) = lo;
        *(bf8*)(outp + (size_t)d * F1 + c0 + 8) = hi;
    }
}

// ---------------- GEMM2: h2 = h1r @ W2 (bf16 in, fp8 out) + fused att dots ----
__global__ __launch_bounds__(256)
void gemm2_k(const u16* __restrict__ A, const u16* __restrict__ Bp,
             const float* __restrict__ att_s, const float* __restrict__ att_d,
             u8* __restrict__ h2f8, float* __restrict__ as2, float* __restrict__ ad2)
{
    const int S = F1 / 32;   // 8
    __shared__ float asl[4][64], adl[4][64];
    int lane = threadIdx.x & 63, w = threadIdx.x >> 6;
    int m0 = blockIdx.x * 64;
    int row_in = lane & 15, kq = lane >> 4;
    f32x4 acc[4];
#pragma unroll
    for (int r = 0; r < 4; r++) acc[r] = (f32x4){0.f, 0.f, 0.f, 0.f};
    int R = (NNODES - m0) >> 4; if (R > 4) R = 4;

    for (int s = 0; s < S; s++) {
        bf8 bfrag = *(const bf8*)(Bp + (((size_t)w * S + s) * 64 + lane) * 8);
        int kb = s * 32 + kq * 8;
        bf8 af[4];
#pragma unroll
        for (int r = 0; r < 4; r++)
            if (r < R) af[r] = *(const bf8*)(A + (size_t)(m0 + r * 16 + row_in) * F1 + kb);
#pragma unroll
        for (int r = 0; r < 4; r++)
            if (r < R)
                acc[r] = __builtin_amdgcn_mfma_f32_16x16x32_bf16(bfrag, af[r], acc[r], 0, 0, 0);
    }
    float attS[4], attD[4];
#pragma unroll
    for (int v = 0; v < 4; v++) {
        attS[v] = att_s[w * 16 + kq * 4 + v];
        attD[v] = att_d[w * 16 + kq * 4 + v];
    }
#pragma unroll
    for (int r = 0; r < 4; r++) {
        if (r >= R) break;
        int node = m0 + r * 16 + row_in;
        unsigned u = pk4fp8(acc[r][0], acc[r][1], acc[r][2], acc[r][3]);
        *(unsigned*)(h2f8 + (size_t)node * HIDN + w * 16 + kq * 4) = u;
        float pa = 0.f, pd = 0.f;
#pragma unroll
        for (int v = 0; v < 4; v++) {
            pa = fmaf(acc[r][v], attS[v], pa);
            pd = fmaf(acc[r][v], attD[v], pd);
        }
        pa += __shfl_xor(pa, 16); pa += __shfl_xor(pa, 32);
        pd += __shfl_xor(pd, 16); pd += __shfl_xor(pd, 32);
        if (kq == 0) { asl[w][r * 16 + row_in] = pa; adl[w][r * 16 + row_in] = pd; }
    }
    __syncthreads();
    int tid = threadIdx.x;
    if (tid < R * 16) {
        as2[m0 + tid] = asl[0][tid] + asl[1][tid] + asl[2][tid] + asl[3][tid];
        ad2[m0 + tid] = adl[0][tid] + adl[1][tid] + adl[2][tid] + adl[3][tid];
    }
}

// ---------------- layer-2 gather: 8 lanes/edge, 8 edges in flight, 2x unroll ---
__global__ __launch_bounds__(256)
void gagg2(const int* __restrict__ rowptr, const int* __restrict__ csr,
           const float* __restrict__ as2, const float* __restrict__ ad2,
           const u8* __restrict__ h2f8, const float* __restrict__ b2,
           const float* __restrict__ aw, const float* __restrict__ ab,
           float* __restrict__ outp, float* __restrict__ scores)
{
    int wid = threadIdx.x >> 6, lane = threadIdx.x & 63;
    int d = blockIdx.x * 4 + wid;
    if (d >= NNODES) return;
    int beg = rowptr[d];
    int tot = rowptr[d + 1] - beg + 1;
    int oct = lane >> 3;
    int l8 = lane & 7;
    int c0 = l8 << 3;
    float ads = ad2[d];
    float den = 0.f;
    float acc[8];
#pragma unroll
    for (int j = 0; j < 8; j++) acc[j] = 0.f;

    const u8* hbase = h2f8 + c0;
    int p = oct;
    for (; p + 8 < tot; p += 16) {
        int s0 = (p == 0) ? d : csr[beg + p - 1];
        int s1 = csr[beg + p + 7];
        uint2 v0 = *(const uint2*)(hbase + (size_t)s0 * HIDN);
        uint2 v1 = *(const uint2*)(hbase + (size_t)s1 * HIDN);
        float e0 = __expf(lrelu(as2[s0] + ads));
        float e1 = __expf(lrelu(as2[s1] + ads));
        den += e0 + e1;
        acc8(e0, v0, acc);
        acc8(e1, v1, acc);
    }
    for (; p < tot; p += 8) {
        int s = (p == 0) ? d : csr[beg + p - 1];
        uint2 v = *(const uint2*)(hbase + (size_t)s * HIDN);
        float ex = __expf(lrelu(as2[s] + ads));
        den += ex;
        acc8(ex, v, acc);
    }
    den += __shfl_xor(den, 8); den += __shfl_xor(den, 16); den += __shfl_xor(den, 32);
#pragma unroll
    for (int j = 0; j < 8; j++) {
        acc[j] += __shfl_xor(acc[j], 8);
        acc[j] += __shfl_xor(acc[j], 16);
        acc[j] += __shfl_xor(acc[j], 32);
    }
    float rden = 1.f / den;
    float o[8];
#pragma unroll
    for (int j = 0; j < 8; j++) o[j] = fmaf(acc[j], rden, b2[c0 + j]);
    if (lane < 8) {
        float4 lo = make_float4(o[0], o[1], o[2], o[3]);
        float4 hi = make_float4(o[4], o[5], o[6], o[7]);
        *(float4*)(outp + (size_t)d * HIDN + c0) = lo;
        *(float4*)(outp + (size_t)d * HIDN + c0 + 4) = hi;
    }
    float p_ = 0.f;
#pragma unroll
    for (int j = 0; j < 8; j++) p_ = fmaf(o[j], aw[c0 + j], p_);
    p_ += __shfl_xor(p_, 1); p_ += __shfl_xor(p_, 2); p_ += __shfl_xor(p_, 4);
    if (lane == 0) scores[d] = tanhf(p_ + ab[0]);
}

// ---------------- masked online-softmax partials + last-block combine ---------
__global__ __launch_bounds__(256)
void partials_k(const float* __restrict__ scores, const int* __restrict__ masks,
                const float* __restrict__ hf, const int* __restrict__ cur_nodes,
                const int* __restrict__ cur_counts, const float* __restrict__ sw,
                const float* __restrict__ sb,
                float* __restrict__ pmax, float* __restrict__ psum,
                int* __restrict__ pcnt,
                float* __restrict__ gmax, float* __restrict__ gsum,
                float* __restrict__ stops)
{
    __shared__ float lm[4], ls[4];
    __shared__ int lastflag;
    int g = blockIdx.y;
    float m = -3.0e38f, s = 0.f;
    for (int n = blockIdx.x * 256 + threadIdx.x; n < NNODES; n += gridDim.x * 256) {
        if (masks[(size_t)g * NNODES + n]) {
            float v = scores[n];
            if (v > m) { s = s * __expf(m - v) + 1.f; m = v; }
            else s += __expf(v - m);
        }
    }
#pragma unroll
    for (int o = 1; o < 64; o <<= 1) {
        float om = __shfl_xor(m, o), os = __shfl_xor(s, o);
        float M = fmaxf(m, om);
        s = s * __expf(m - M) + os * __expf(om - M);
        m = M;
    }
    if ((threadIdx.x & 63) == 0) { lm[threadIdx.x >> 6] = m; ls[threadIdx.x >> 6] = s; }
    __syncthreads();
    if (threadIdx.x == 0) {
        float M = m, S = s;
        for (int w_ = 1; w_ < 4; w_++) {
            float M2 = fmaxf(M, lm[w_]);
            S = S * __expf(M - M2) + ls[w_] * __expf(lm[w_] - M2);
            M = M2;
        }
        pmax[g * 64 + blockIdx.x] = M;
        psum[g * 64 + blockIdx.x] = S;
        __threadfence();
        int old = atomicAdd(&pcnt[g], 1);
        lastflag = (old == 63);
    }
    __syncthreads();
    if (!lastflag) return;

    int tid = threadIdx.x;
    if (tid < 64) {
        int cnt = cur_counts[g];
        float cs = 0.f;
        for (int k = 0; k < KCUR; k++)
            if (k < cnt) cs += hf[(size_t)cur_nodes[g * KCUR + k] * HIDN + tid];
        float ctx = cs / (float)(cnt > 1 ? cnt : 1);
        float p = ctx * sw[tid];
#pragma unroll
        for (int o = 1; o < 64; o <<= 1) p += __shfl_xor(p, o);
        float stop = tanhf(p + sb[0]);

        float mm = pmax[g * 64 + tid], sm = psum[g * 64 + tid];
#pragma unroll
        for (int o = 1; o < 64; o <<= 1) {
            float om = __shfl_xor(mm, o), os = __shfl_xor(sm, o);
            float M = fmaxf(mm, om);
            sm = sm * __expf(mm - M) + os * __expf(om - M);
            mm = M;
        }
        if (tid == 0) {
            float M2 = fmaxf(mm, stop);
            float S2 = sm * __expf(mm - M2) + __expf(stop - M2);
            gmax[g] = M2; gsum[g] = S2; stops[g] = stop;
        }
    }
}

// ---------------- final probability write ----------------
__global__ __launch_bounds__(256)
void write_k(const float* __restrict__ scores, const int* __restrict__ masks,
             const float* __restrict__ gmax, const float* __restrict__ gsum,
             const float* __restrict__ stops, const int* __restrict__ cur_counts,
             float* __restrict__ out)
{
    int g = blockIdx.y;
    int j = blockIdx.x * 256 + threadIdx.x;
    if (j > NNODES) return;
    float v;
    if (cur_counts[g] == 0) {
        v = (j == NNODES) ? 1.f : 0.f;
    } else {
        float m = gmax[g];
        float Z = gsum[g];
        if (j == NNODES) v = __expf(stops[g] - m) / Z;
        else v = masks[(size_t)g * NNODES + j] ? __expf(scores[j] - m) / Z : 0.f;
    }
    out[(size_t)g * (NNODES + 1) + j] = v;
}

extern "C" void kernel_launch(void* const* d_in, const int* in_sizes, int n_in,
                              void* d_out, int out_size, void* d_ws, size_t ws_size,
                              hipStream_t stream) {
    const float* x        = (const float*)d_in[0];
    const int* ei         = (const int*)d_in[1];
    const int* cur_nodes  = (const int*)d_in[2];
    const int* cur_counts = (const int*)d_in[3];
    const int* masks      = (const int*)d_in[4];
    const float* W1       = (const float*)d_in[5];
    const float* att_s1   = (const float*)d_in[6];
    const float* att_d1   = (const float*)d_in[7];
    const float* b1       = (const float*)d_in[8];
    const float* W2       = (const float*)d_in[9];
    const float* att_s2   = (const float*)d_in[10];
    const float* att_d2   = (const float*)d_in[11];
    const float* b2       = (const float*)d_in[12];
    const float* action_w = (const float*)d_in[13];
    const float* action_b = (const float*)d_in[14];
    const float* stop_w   = (const float*)d_in[15];
    const float* stop_b   = (const float*)d_in[16];
    float* out = (float*)d_out;

    const int* srcp = ei;
    const int* dstp = ei + NEDGES;

    // ---- workspace layout ----
    int* deg  = (int*)d_ws;                                  // 50000 (zeroed)
    int* pcnt = deg + NNODES;                                // 32 (zeroed)
    char* zend = (char*)(pcnt + GG);
    size_t zbytes = zend - (char*)d_ws;
    int* csum   = (int*)zend;                                // 256
    int* rowptr = csum + 256;                                // 50001 (+3 pad)
    int* cursor = rowptr + NNODES + 4;                       // 50000
    int* csr    = cursor + NNODES;                           // 800000
    u16* W1p    = (u16*)(csr + NEDGES);                      // 32768
    u16* W2p    = W1p + 32768;                               // 16384
    u8*  h1f8   = (u8*)(W2p + 16384);                        // N*256
    u16* h1rb   = (u16*)(h1f8 + (size_t)NNODES * F1);        // N*256 bf16
    u8*  h2f8   = (u8*)(h1rb + (size_t)NNODES * F1);         // N*64
    float* as1  = (float*)(h2f8 + (size_t)NNODES * HIDN);    // N*4
    float* ad1  = as1 + (size_t)NNODES * 4;                  // N*4
    float* as2  = ad1 + (size_t)NNODES * 4;                  // N
    float* ad2  = as2 + NNODES;                              // N
    float* hf   = ad2 + NNODES;                              // N*64
    float* scores = hf + (size_t)NNODES * HIDN;              // N
    float* stops  = scores + NNODES;                         // G
    float* pmax = stops + GG;                                // G*64
    float* psum = pmax + GG * 64;                            // G*64
    float* gmax = psum + GG * 64;                            // G
    float* gsum = gmax + GG;                                 // G
    size_t total = (char*)(gsum + GG) - (char*)d_ws;
    if (total > ws_size) return;

    auto cdiv = [](long long a, long long b) { return (int)((a + b - 1) / b); };

    (void)hipMemsetAsync(deg, 0, zbytes, stream);

    hist_pack_k<<<HBLK + 192, 256, 0, stream>>>(dstp, deg, W1, W2, W1p, W2p);
    chunksum_k<<<NCHUNK, 256, 0, stream>>>(deg, csum);
    expand_k<<<NCHUNK, 256, 0, stream>>>(deg, csum, rowptr, cursor);
    scatter_k<<<HBLK, 256, 0, stream>>>(srcp, dstp, cursor, csr);
    gemm1_k<<<cdiv(NNODES, 64), 256, 0, stream>>>(x, W1p, att_s1, att_d1, h1f8, as1, ad1);
    gagg1<<<cdiv(NNODES, 4), 256, 0, stream>>>(rowptr, csr, as1, ad1, h1f8, b1, h1rb);
    gemm2_k<<<cdiv(NNODES, 64), 256, 0, stream>>>(h1rb, W2p, att_s2, att_d2, h2f8, as2, ad2);
    gagg2<<<cdiv(NNODES, 4), 256, 0, stream>>>(rowptr, csr, as2, ad2, h2f8, b2,
                                               action_w, action_b, hf, scores);
    partials_k<<<dim3(64, GG), 256, 0, stream>>>(scores, masks, hf, cur_nodes, cur_counts,
                                                 stop_w, stop_b, pmax, psum, pcnt,
                                                 gmax, gsum, stops);
    write_k<<<dim3(cdiv(NNODES + 1, 256), GG), 256, 0, stream>>>(scores, masks, gmax, gsum,
                                                                 stops, cur_counts, out);
}